// Round 2
// baseline (763.546 us; speedup 1.0000x reference)
//
#include <hip/hip_runtime.h>
#include <stdint.h>

// MultiAttention fused kernel for MI355X (gfx950) — round 2
// B=131072 rows; D=105 (80 hm + 20 me + 5 tf); 10 attention groups.
// out  [B,105] fp32  (first 13,762,560 floats of d_out)
// alpha[B,1050] fp32 (next 137,625,600 floats of d_out)
//
// R2 change: weights pre-packed in wave-fragment order in ws; MFMA operands
// loaded straight from global (L2-resident, 1KB/wave coalesced). No sW LDS,
// ONE barrier per block -> latency-bound fix (was 40 barriers @ 8 waves/CU).

#define NATT 10
#define DD   105
#define NPAD 112          // padded group width (7 x 16)
#define KP   136          // ctx k pitch in elements (16B-aligned rows)
#define RPB  128          // rows per block
#define FRAG_PER_G (4*7)  // c x T fragments per group per operand
#define FRAG_ELEMS 512    // 64 lanes x 8 bf16
#define OP_ELEMS (NATT*FRAG_PER_G*FRAG_ELEMS)   // 143360 bf16 per operand pack

typedef __attribute__((ext_vector_type(8))) short short8v;  // 8 bf16 = MFMA A/B frag
typedef __attribute__((ext_vector_type(4))) short short4v;
typedef __attribute__((ext_vector_type(4))) float f4;

__device__ __forceinline__ short f2bf(float x) {
  unsigned int u = __builtin_bit_cast(unsigned int, x);
  unsigned int r = (u + 0x7FFFu + ((u >> 16) & 1u)) >> 16;   // RNE
  return (short)(r & 0xFFFFu);
}
__device__ __forceinline__ float bf2f(int b) {
  unsigned int u = ((unsigned int)(b & 0xFFFF)) << 16;
  return __builtin_bit_cast(float, u);
}

// ---------------- prep: build bf16 fragment packs in workspace ----------------
// Afrag[g][c][T][lane][j]: A-operand for GEMM1. Lane l, elem j holds
//   A_w[(g*105 + T*16 + (l&15))*105 + (c*32 + (l>>4)*8 + j)], 0 outside.
// Wfrag[g][cc][jt][lane][j]: B-operand for GEMM2 (block-diag [HM|ME|TF]),
//   kappa2-consistent with the h fragment layout:
//   ilp = cc*32 + (l>>4)*8 + j ; il = cc*32 + gg*4 + (jj&3) + 16*(jj>>2)
//   value = Wall[jt*16+(l&15)][g*105 + il]  (0 for il>=105)
// Abp [g][n<112] fp32: A_b, pad = -1e30 (masks softmax pad cols)
// Bout[112] fp32: [HM_b|ME_b|TF_b|0]
// Lut [1152] u16: expanded-column -> ctx column map
__global__ void prep_kernel(const float* __restrict__ Aw, const float* __restrict__ Ab,
                            const float* __restrict__ HMw, const float* __restrict__ HMb,
                            const float* __restrict__ MEw, const float* __restrict__ MEb,
                            const float* __restrict__ TFw, const float* __restrict__ TFb,
                            short* __restrict__ Afrag, short* __restrict__ Wfrag,
                            float* __restrict__ Abp, float* __restrict__ Bout,
                            unsigned short* __restrict__ Lut)
{
  int tid = blockIdx.x * blockDim.x + threadIdx.x;
  int NT  = gridDim.x * blockDim.x;

  for (int a = tid; a < OP_ELEMS; a += NT) {
    int j = a & 7, l = (a >> 3) & 63;
    int rem = a >> 9;            // g*28 + c*7 + T
    int T = rem % 7, rem2 = rem / 7;
    int c = rem2 & 3, g = rem2 >> 2;
    int n = T * 16 + (l & 15);
    int k = c * 32 + (l >> 4) * 8 + j;
    float v = 0.f;
    if (n < DD && k < DD) v = Aw[(g * DD + n) * DD + k];
    Afrag[a] = f2bf(v);
  }

  for (int a = tid; a < OP_ELEMS; a += NT) {
    int j = a & 7, l = (a >> 3) & 63;
    int rem = a >> 9;
    int jt = rem % 7, rem2 = rem / 7;
    int cc = rem2 & 3, g = rem2 >> 2;
    int jout = jt * 16 + (l & 15);
    int gg = l >> 4, jj = j;
    int il = cc * 32 + gg * 4 + (jj & 3) + ((jj >> 2) << 4);
    float v = 0.f;
    if (il < DD && jout < DD) {
      int i = g * DD + il;
      if (i < 800)       { if (jout < 80)               v = HMw[jout * 800 + i]; }
      else if (i < 1000) { if (jout >= 80 && jout < 100) v = MEw[(jout - 80) * 200 + (i - 800)]; }
      else               { if (jout >= 100)              v = TFw[(jout - 100) * 50 + (i - 1000)]; }
    }
    Wfrag[a] = f2bf(v);
  }

  for (int a = tid; a < NATT * NPAD; a += NT) {
    int g = a / NPAD; int n = a - g * NPAD;
    Abp[a] = (n < DD) ? Ab[g * DD + n] : -1e30f;
  }

  for (int a = tid; a < NPAD; a += NT) {
    float v = 0.f;
    if (a < 80) v = HMb[a];
    else if (a < 100) v = MEb[a - 80];
    else if (a < DD)  v = TFb[a - 100];
    Bout[a] = v;
  }

  for (int a = tid; a < 1152; a += NT) {
    int col;
    if (a < 800)       col = a % 80;
    else if (a < 1000) col = 80 + (a - 800) % 20;
    else if (a < 1050) col = 100 + (a - 1000) % 5;
    else               col = 100;  // only reached where alpha==0
    Lut[a] = (unsigned short)col;
  }
}

// ---------------- main fused kernel ----------------
// 1024 blocks x 256 threads; 4 waves x 32 rows each; ONE barrier.
// LDS: sCtx 128x136 bf16 (34816B) + sLut 1152 u16 (2304B) = 37120B.
__global__ __launch_bounds__(256, 3)
void fused_main(const float* __restrict__ hm, const float* __restrict__ me,
                const float* __restrict__ tf,
                const short* __restrict__ Afrag, const short* __restrict__ Wfrag,
                const float* __restrict__ Abp, const float* __restrict__ Bout,
                const unsigned short* __restrict__ Lut,
                float* __restrict__ out, float* __restrict__ alphaOut)
{
  __shared__ short sCtx[RPB * KP];
  __shared__ unsigned short sLut[1152];

  const int tid  = threadIdx.x;
  const int lane = tid & 63;
  const int wave = tid >> 6;
  const int l15  = lane & 15;
  const int g16  = lane >> 4;
  const long rowbase = (long)blockIdx.x * RPB;

  // ---- stage ctx tile as bf16: [row][0..79]=hm [80..99]=me [100..104]=tf [105..135]=0 ----
  for (int q = tid; q < (RPB * 80) / 4; q += 256) {
    f4 v = *(const f4*)(hm + rowbase * 80 + q * 4);
    int r = (q * 4) / 80, c = (q * 4) % 80;
    short4v b; b[0]=f2bf(v[0]); b[1]=f2bf(v[1]); b[2]=f2bf(v[2]); b[3]=f2bf(v[3]);
    *(short4v*)&sCtx[r * KP + c] = b;
  }
  for (int q = tid; q < (RPB * 20) / 4; q += 256) {
    f4 v = *(const f4*)(me + rowbase * 20 + q * 4);
    int r = (q * 4) / 20, c = (q * 4) % 20;
    short4v b; b[0]=f2bf(v[0]); b[1]=f2bf(v[1]); b[2]=f2bf(v[2]); b[3]=f2bf(v[3]);
    *(short4v*)&sCtx[r * KP + 80 + c] = b;
  }
  for (int q = tid; q < RPB * 5; q += 256) {
    float v = tf[rowbase * 5 + q];
    int r = q / 5, c = q - r * 5;
    sCtx[r * KP + 100 + c] = f2bf(v);
  }
  for (int q = tid; q < RPB * 31; q += 256) {
    int r = q / 31, c = q - r * 31;
    sCtx[r * KP + 105 + c] = 0;
  }
  for (int q = tid; q < 1152; q += 256) sLut[q] = Lut[q];

  __syncthreads();   // the only barrier

  f4 acc2[2][7];
  #pragma unroll
  for (int rt = 0; rt < 2; ++rt)
    #pragma unroll
    for (int jt = 0; jt < 7; ++jt) {
      acc2[rt][jt][0]=0.f; acc2[rt][jt][1]=0.f; acc2[rt][jt][2]=0.f; acc2[rt][jt][3]=0.f;
    }

  short8v hf[2][4];   // h fragments (GEMM2 A operand), per row-tile, per 32-wide k chunk

  for (int g = 0; g < NATT; ++g) {
    const short* Ag = Afrag + g * FRAG_PER_G * FRAG_ELEMS;
    const short* Wg = Wfrag + g * FRAG_PER_G * FRAG_ELEMS;

    // ---- GEMM1 (swapped): z^T tile; D[n][r], n=16T+4*g16+reg, r=l15 ----
    f4 za[2][7];
    #pragma unroll
    for (int rt = 0; rt < 2; ++rt)
      #pragma unroll
      for (int T = 0; T < 7; ++T) { za[rt][T][0]=0.f; za[rt][T][1]=0.f; za[rt][T][2]=0.f; za[rt][T][3]=0.f; }

    #pragma unroll
    for (int c = 0; c < 4; ++c) {
      short8v cf0 = *(const short8v*)&sCtx[(wave * 32 +      l15) * KP + c * 32 + g16 * 8];
      short8v cf1 = *(const short8v*)&sCtx[(wave * 32 + 16 + l15) * KP + c * 32 + g16 * 8];
      #pragma unroll
      for (int T = 0; T < 7; ++T) {
        short8v af = *(const short8v*)(Ag + (c * 7 + T) * FRAG_ELEMS + lane * 8);
        za[0][T] = __builtin_amdgcn_mfma_f32_16x16x32_bf16(af, cf0, za[0][T], 0, 0, 0);
        za[1][T] = __builtin_amdgcn_mfma_f32_16x16x32_bf16(af, cf1, za[1][T], 0, 0, 0);
      }
    }

    // ---- softmax + alpha store + h build (per 16-row tile), in-place in za ----
    #pragma unroll
    for (int rt = 0; rt < 2; ++rt) {
      float mx = -3e38f;
      #pragma unroll
      for (int T = 0; T < 7; ++T) {
        f4 ab = *(const f4*)(Abp + g * NPAD + T * 16 + g16 * 4);
        #pragma unroll
        for (int k = 0; k < 4; ++k) {
          float v = za[rt][T][k] + ab[k];   // pad cols get -1e30 -> masked
          za[rt][T][k] = v;
          mx = fmaxf(mx, v);
        }
      }
      mx = fmaxf(mx, __shfl_xor(mx, 16));
      mx = fmaxf(mx, __shfl_xor(mx, 32));
      float s = 0.f;
      #pragma unroll
      for (int T = 0; T < 7; ++T)
        #pragma unroll
        for (int k = 0; k < 4; ++k) {
          float p = __expf(za[rt][T][k] - mx);
          za[rt][T][k] = p;
          s += p;
        }
      s += __shfl_xor(s, 16);
      s += __shfl_xor(s, 32);
      float inv = __fdividef(1.f, s);

      const int rowl = wave * 32 + rt * 16 + l15;
      float* arow = alphaOut + (rowbase + rowl) * 1050 + g * DD;

      hf[rt][3][4] = 0; hf[rt][3][5] = 0; hf[rt][3][6] = 0; hf[rt][3][7] = 0; // T=7 half
      #pragma unroll
      for (int T = 0; T < 7; ++T) {
        #pragma unroll
        for (int k = 0; k < 4; ++k) {
          float a = za[rt][T][k] * inv;
          int n = T * 16 + g16 * 4 + k;
          if (T < 6)        arow[n] = a;
          else if (n < DD)  arow[n] = a;
          int i = g * DD + n;                        // absolute expanded column
          int col = sLut[i];                         // ctx column (LDS-hot LUT)
          float e = bf2f(sCtx[rowl * KP + col]);     // gather modality value
          short hb = f2bf(a * e);
          hf[rt][T >> 1][(T & 1) * 4 + k] = hb;      // kappa2 slot
        }
      }
    }

    // ---- GEMM2 accumulate: out[r][j] += sum_il h[r][105g+il] * Wall[j][105g+il] ----
    #pragma unroll
    for (int cc = 0; cc < 4; ++cc) {
      #pragma unroll
      for (int jt = 0; jt < 7; ++jt) {
        short8v wf = *(const short8v*)(Wg + (cc * 7 + jt) * FRAG_ELEMS + lane * 8);
        acc2[0][jt] = __builtin_amdgcn_mfma_f32_16x16x32_bf16(hf[0][cc], wf, acc2[0][jt], 0, 0, 0);
        acc2[1][jt] = __builtin_amdgcn_mfma_f32_16x16x32_bf16(hf[1][cc], wf, acc2[1][jt], 0, 0, 0);
      }
    }
  }

  // ---- epilogue: out = acc2 + bias; D2[r][j]: r = rt*16+4*g16+k, j = 16*jt+l15 ----
  #pragma unroll
  for (int jt = 0; jt < 7; ++jt) {
    int j = jt * 16 + l15;
    if (j < DD) {
      float bj = Bout[j];
      #pragma unroll
      for (int rt = 0; rt < 2; ++rt)
        #pragma unroll
        for (int k = 0; k < 4; ++k) {
          long row = rowbase + wave * 32 + rt * 16 + g16 * 4 + k;
          out[row * DD + j] = acc2[rt][jt][k] + bj;
        }
    }
  }
}

// ---------------- launch ----------------
extern "C" void kernel_launch(void* const* d_in, const int* in_sizes, int n_in,
                              void* d_out, int out_size, void* d_ws, size_t ws_size,
                              hipStream_t stream)
{
  const float* hm  = (const float*)d_in[0];
  const float* me  = (const float*)d_in[1];
  const float* tf  = (const float*)d_in[2];
  const float* Aw  = (const float*)d_in[3];
  const float* Ab  = (const float*)d_in[4];
  const float* HMw = (const float*)d_in[5];
  const float* HMb = (const float*)d_in[6];
  const float* MEw = (const float*)d_in[7];
  const float* MEb = (const float*)d_in[8];
  const float* TFw = (const float*)d_in[9];
  const float* TFb = (const float*)d_in[10];

  char* ws = (char*)d_ws;
  short* Afrag = (short*)(ws + 0);                 // 286720 B
  short* Wfrag = (short*)(ws + 286720);            // 286720 B
  float* Abp   = (float*)(ws + 573440);            // 4480 B
  float* BoutP = (float*)(ws + 577920);            // 448 B
  unsigned short* Lut = (unsigned short*)(ws + 578368); // 2304 B (total 580672)

  float* outP     = (float*)d_out;
  float* alphaOut = outP + (long)131072 * DD;

  prep_kernel<<<320, 256, 0, stream>>>(Aw, Ab, HMw, HMb, MEw, MEb, TFw, TFb,
                                       Afrag, Wfrag, Abp, BoutP, Lut);
  fused_main<<<1024, 256, 0, stream>>>(hm, me, tf, Afrag, Wfrag, Abp, BoutP, Lut,
                                       outP, alphaOut);
}

// Round 3
// 307.216 us; speedup vs baseline: 2.4854x; 2.4854x over previous
//
#include <hip/hip_runtime.h>
#include <stdint.h>

// MultiAttention fused kernel for MI355X (gfx950) — round 3
// B=131072 rows; D=105 (80 hm + 20 me + 5 tf); 10 attention groups.
// out  [B,105] fp32  (first 13,762,560 floats of d_out)
// alpha[B,1050] fp32 (next 137,625,600 floats of d_out)
//
// R3: barrier-free waves (wave-private ctx staging), frag-packed weights from
// L2 with explicit 2-stage prefetch pipeline, launch_bounds(256,2) so no
// spills (R2 failed on 84-VGPR cap -> scratch), bias folded into both GEMMs,
// dwordx4 alpha stores.

#define NATT 10
#define DD   105
#define KP   136          // ctx k pitch in elements
#define RPB  128          // rows per block (4 waves x 32)
#define FRAG_PER_G (4*7)  // c x T fragments per group per operand
#define FRAG_ELEMS 512    // 64 lanes x 8 bf16
#define OP_ELEMS (NATT*FRAG_PER_G*FRAG_ELEMS)   // 143360 bf16 per operand pack

typedef __attribute__((ext_vector_type(8))) short short8v;  // 8 bf16 = MFMA A/B frag
typedef __attribute__((ext_vector_type(4))) short short4v;
typedef __attribute__((ext_vector_type(4))) float f4;
typedef float f4u __attribute__((ext_vector_type(4), aligned(4)));  // 4B-aligned vec store

__device__ __forceinline__ short f2bf(float x) {
  unsigned int u = __builtin_bit_cast(unsigned int, x);
  unsigned int r = (u + 0x7FFFu + ((u >> 16) & 1u)) >> 16;   // RNE
  return (short)(r & 0xFFFFu);
}
__device__ __forceinline__ float bf2f(int b) {
  unsigned int u = ((unsigned int)(b & 0xFFFF)) << 16;
  return __builtin_bit_cast(float, u);
}

// ---------------- prep: build bf16 fragment packs in workspace ----------------
// Afrag[g][c][T][lane][j]: GEMM1 A-operand. Lane l elem j:
//   n = T*16+(l&15), k = c*32+(l>>4)*8+j
//   k<105:  A_w[(g*105+n)*105+k]        (0 if n>=105)
//   k==105: A_b[g*105+n] if n<105 else -1e30   (bias fold via ctx col105==1.0)
//   k>105:  0
// Wfrag[g][cc][jt][lane][j]: GEMM2 B-operand, kappa2 k-slot map:
//   il = cc*32 + (l>>4)*4 + (j&3) + 16*(j>>2); jout = jt*16+(l&15)
//   il<105:  block-diag [HM|ME|TF] weight at (jout, g*105+il)
//   il==105 && g==0: out-bias[jout]     (h slot forced to 1.0 at g==0)
// Lut [1152] u16: expanded-column -> ctx column map
__global__ void prep_kernel(const float* __restrict__ Aw, const float* __restrict__ Ab,
                            const float* __restrict__ HMw, const float* __restrict__ HMb,
                            const float* __restrict__ MEw, const float* __restrict__ MEb,
                            const float* __restrict__ TFw, const float* __restrict__ TFb,
                            short* __restrict__ Afrag, short* __restrict__ Wfrag,
                            unsigned short* __restrict__ Lut)
{
  int tid = blockIdx.x * blockDim.x + threadIdx.x;
  int NT  = gridDim.x * blockDim.x;

  for (int a = tid; a < OP_ELEMS; a += NT) {
    int j = a & 7, l = (a >> 3) & 63;
    int rem = a >> 9;            // g*28 + c*7 + T
    int T = rem % 7, rem2 = rem / 7;
    int c = rem2 & 3, g = rem2 >> 2;
    int n = T * 16 + (l & 15);
    int k = c * 32 + (l >> 4) * 8 + j;
    float v = 0.f;
    if (n < DD && k < DD) v = Aw[(g * DD + n) * DD + k];
    else if (k == DD)     v = (n < DD) ? Ab[g * DD + n] : -1e30f;
    Afrag[a] = f2bf(v);
  }

  for (int a = tid; a < OP_ELEMS; a += NT) {
    int j = a & 7, l = (a >> 3) & 63;
    int rem = a >> 9;
    int jt = rem % 7, rem2 = rem / 7;
    int cc = rem2 & 3, g = rem2 >> 2;
    int jout = jt * 16 + (l & 15);
    int gg = l >> 4;
    int il = cc * 32 + gg * 4 + (j & 3) + ((j >> 2) << 4);
    float v = 0.f;
    if (il < DD && jout < DD) {
      int i = g * DD + il;
      if (i < 800)       { if (jout < 80)                v = HMw[jout * 800 + i]; }
      else if (i < 1000) { if (jout >= 80 && jout < 100) v = MEw[(jout - 80) * 200 + (i - 800)]; }
      else               { if (jout >= 100)              v = TFw[(jout - 100) * 50 + (i - 1000)]; }
    } else if (il == DD && g == 0 && jout < DD) {
      if (jout < 80)       v = HMb[jout];
      else if (jout < 100) v = MEb[jout - 80];
      else                 v = TFb[jout - 100];
    }
    Wfrag[a] = f2bf(v);
  }

  for (int a = tid; a < 1152; a += NT) {
    int col;
    if (a < 800)       col = a % 80;
    else if (a < 1000) col = 80 + (a - 800) % 20;
    else if (a < 1050) col = 100 + (a - 1000) % 5;
    else               col = 100;  // alpha==0 there
    Lut[a] = (unsigned short)col;
  }
}

// ---------------- main fused kernel ----------------
// 1024 blocks x 256 threads; 4 waves x 32 rows; ZERO barriers.
// LDS: sCtx 128x136 bf16 (34816B) + sLut 1152 u16 (2304B) = 37120B.
__global__ __launch_bounds__(256, 2)
void fused_main(const float* __restrict__ hm, const float* __restrict__ me,
                const float* __restrict__ tf,
                const short* __restrict__ Afrag, const short* __restrict__ Wfrag,
                const unsigned short* __restrict__ Lut,
                float* __restrict__ out, float* __restrict__ alphaOut)
{
  __shared__ short sCtx[RPB * KP];
  __shared__ unsigned short sLut[1152];

  const int tid  = threadIdx.x;
  const int lane = tid & 63;
  const int wave = tid >> 6;
  const int l15  = lane & 15;
  const int g16  = lane >> 4;
  const long rowbase = (long)blockIdx.x * RPB;
  const int wrow0 = wave * 32;     // this wave's first local row

  // ---- wave-private ctx staging (rows wrow0..wrow0+31 only) ----
  for (int q = lane; q < 32 * 20; q += 64) {        // hm: 20 f4 per row
    int r = q / 20, c = q - r * 20;
    f4 v = *(const f4*)(hm + (rowbase + wrow0 + r) * 80 + c * 4);
    short4v b; b[0]=f2bf(v[0]); b[1]=f2bf(v[1]); b[2]=f2bf(v[2]); b[3]=f2bf(v[3]);
    *(short4v*)&sCtx[(wrow0 + r) * KP + c * 4] = b;
  }
  for (int q = lane; q < 32 * 5; q += 64) {         // me: 5 f4 per row
    int r = q / 5, c = q - r * 5;
    f4 v = *(const f4*)(me + (rowbase + wrow0 + r) * 20 + c * 4);
    short4v b; b[0]=f2bf(v[0]); b[1]=f2bf(v[1]); b[2]=f2bf(v[2]); b[3]=f2bf(v[3]);
    *(short4v*)&sCtx[(wrow0 + r) * KP + 80 + c * 4] = b;
  }
  for (int q = lane; q < 32 * 5; q += 64) {         // tf: 5 scalars per row
    int r = q / 5, c = q - r * 5;
    sCtx[(wrow0 + r) * KP + 100 + c] = f2bf(tf[(rowbase + wrow0 + r) * 5 + c]);
  }
  for (int q = lane; q < 32 * 31; q += 64) {        // pad cols 105..135; col105 = 1.0
    int r = q / 31, c = q - r * 31;
    sCtx[(wrow0 + r) * KP + 105 + c] = (c == 0) ? (short)0x3F80 : (short)0;
  }
  for (int q = lane; q < 1152; q += 64) sLut[q] = Lut[q];  // identical redundant writes

  // ---- preload ctx MFMA fragments (group-invariant) ----
  short8v cf0[4], cf1[4];
  #pragma unroll
  for (int c = 0; c < 4; ++c) {
    cf0[c] = *(const short8v*)&sCtx[(wrow0 +      l15) * KP + c * 32 + g16 * 8];
    cf1[c] = *(const short8v*)&sCtx[(wrow0 + 16 + l15) * KP + c * 32 + g16 * 8];
  }

  f4 acc2[2][7];
  #pragma unroll
  for (int rt = 0; rt < 2; ++rt)
    #pragma unroll
    for (int jt = 0; jt < 7; ++jt) {
      acc2[rt][jt][0]=0.f; acc2[rt][jt][1]=0.f; acc2[rt][jt][2]=0.f; acc2[rt][jt][3]=0.f;
    }

  const short* Afl = Afrag + lane * 8;
  const short* Wfl = Wfrag + lane * 8;

  for (int g = 0; g < NATT; ++g) {
    const short* Ag = Afl + g * FRAG_PER_G * FRAG_ELEMS;
    const short* Wg = Wfl + g * FRAG_PER_G * FRAG_ELEMS;

    // ---- GEMM1 (swapped): z tile D[n][r], n=16T+4*g16+reg, r=l15; 2-stage pipeline ----
    f4 za[2][7];
    #pragma unroll
    for (int rt = 0; rt < 2; ++rt)
      #pragma unroll
      for (int T = 0; T < 7; ++T) { za[rt][T][0]=0.f; za[rt][T][1]=0.f; za[rt][T][2]=0.f; za[rt][T][3]=0.f; }

    short8v afc[7], afn[7];
    #pragma unroll
    for (int T = 0; T < 7; ++T) afc[T] = *(const short8v*)(Ag + T * FRAG_ELEMS);
    #pragma unroll
    for (int c = 0; c < 4; ++c) {
      if (c < 3) {
        #pragma unroll
        for (int T = 0; T < 7; ++T) afn[T] = *(const short8v*)(Ag + ((c + 1) * 7 + T) * FRAG_ELEMS);
      }
      #pragma unroll
      for (int T = 0; T < 7; ++T) {
        za[0][T] = __builtin_amdgcn_mfma_f32_16x16x32_bf16(afc[T], cf0[c], za[0][T], 0, 0, 0);
        za[1][T] = __builtin_amdgcn_mfma_f32_16x16x32_bf16(afc[T], cf1[c], za[1][T], 0, 0, 0);
      }
      if (c < 3) {
        #pragma unroll
        for (int T = 0; T < 7; ++T) afc[T] = afn[T];
      }
    }

    // ---- prefetch GEMM2 cc=0 B-frags (hide under softmax) ----
    short8v wfc[7], wfn[7];
    #pragma unroll
    for (int T = 0; T < 7; ++T) wfc[T] = *(const short8v*)(Wg + T * FRAG_ELEMS);

    // ---- softmax (bias already in z via ctx col105) + alpha store + h build ----
    short8v hf[2][4];
    #pragma unroll
    for (int rt = 0; rt < 2; ++rt) {
      float mx = -3e38f;
      #pragma unroll
      for (int T = 0; T < 7; ++T)
        #pragma unroll
        for (int k = 0; k < 4; ++k) mx = fmaxf(mx, za[rt][T][k]);
      mx = fmaxf(mx, __shfl_xor(mx, 16));
      mx = fmaxf(mx, __shfl_xor(mx, 32));
      float s = 0.f;
      #pragma unroll
      for (int T = 0; T < 7; ++T)
        #pragma unroll
        for (int k = 0; k < 4; ++k) {
          float p = __expf(za[rt][T][k] - mx);   // pad cols: z=-1e30 -> p=0
          za[rt][T][k] = p;
          s += p;
        }
      s += __shfl_xor(s, 16);
      s += __shfl_xor(s, 32);
      float inv = __fdividef(1.f, s);

      const int rowl = wrow0 + rt * 16 + l15;
      float* arow = alphaOut + (rowbase + rowl) * 1050 + g * DD;
      const short* crow = &sCtx[rowl * KP];

      hf[rt][3][4] = 0; hf[rt][3][5] = 0; hf[rt][3][6] = 0; hf[rt][3][7] = 0;
      #pragma unroll
      for (int T = 0; T < 7; ++T) {
        f4 av = za[rt][T] * inv;
        int n0 = T * 16 + g16 * 4;
        if (T < 6) {
          *(f4u*)(arow + n0) = av;               // dwordx4, 4B-aligned OK
        } else {
          if (g16 < 2)       *(f4u*)(arow + n0) = av;
          else if (g16 == 2) arow[104] = av[0];  // n=104 only; n>=105 masked
        }
        #pragma unroll
        for (int k = 0; k < 4; ++k) {
          int i = g * DD + n0 + k;
          float e = bf2f(crow[sLut[i]]);
          hf[rt][T >> 1][(T & 1) * 4 + k] = f2bf(av[k] * e);
        }
      }
    }
    if (g == 0 && g16 == 2) {      // il=105 slot := 1.0 -> GEMM2 adds out-bias once
      hf[0][3][1] = (short)0x3F80;
      hf[1][3][1] = (short)0x3F80;
    }

    // ---- GEMM2 accumulate (2-stage pipeline) ----
    #pragma unroll
    for (int cc = 0; cc < 4; ++cc) {
      if (cc < 3) {
        #pragma unroll
        for (int T = 0; T < 7; ++T) wfn[T] = *(const short8v*)(Wg + ((cc + 1) * 7 + T) * FRAG_ELEMS);
      }
      #pragma unroll
      for (int jt = 0; jt < 7; ++jt) {
        acc2[0][jt] = __builtin_amdgcn_mfma_f32_16x16x32_bf16(hf[0][cc], wfc[jt], acc2[0][jt], 0, 0, 0);
        acc2[1][jt] = __builtin_amdgcn_mfma_f32_16x16x32_bf16(hf[1][cc], wfc[jt], acc2[1][jt], 0, 0, 0);
      }
      if (cc < 3) {
        #pragma unroll
        for (int T = 0; T < 7; ++T) wfc[T] = wfn[T];
      }
    }
  }

  // ---- epilogue: bias already in acc2; D2[r][j]: r=rt*16+4*g16+k, j=16*jt+l15 ----
  #pragma unroll
  for (int jt = 0; jt < 7; ++jt) {
    int j = jt * 16 + l15;
    if (j < DD) {
      #pragma unroll
      for (int rt = 0; rt < 2; ++rt)
        #pragma unroll
        for (int k = 0; k < 4; ++k) {
          long row = rowbase + wrow0 + rt * 16 + g16 * 4 + k;
          out[row * DD + j] = acc2[rt][jt][k];
        }
    }
  }
}

// ---------------- launch ----------------
extern "C" void kernel_launch(void* const* d_in, const int* in_sizes, int n_in,
                              void* d_out, int out_size, void* d_ws, size_t ws_size,
                              hipStream_t stream)
{
  const float* hm  = (const float*)d_in[0];
  const float* me  = (const float*)d_in[1];
  const float* tf  = (const float*)d_in[2];
  const float* Aw  = (const float*)d_in[3];
  const float* Ab  = (const float*)d_in[4];
  const float* HMw = (const float*)d_in[5];
  const float* HMb = (const float*)d_in[6];
  const float* MEw = (const float*)d_in[7];
  const float* MEb = (const float*)d_in[8];
  const float* TFw = (const float*)d_in[9];
  const float* TFb = (const float*)d_in[10];

  char* ws = (char*)d_ws;
  short* Afrag = (short*)(ws + 0);                 // 286720 B
  short* Wfrag = (short*)(ws + 286720);            // 286720 B
  unsigned short* Lut = (unsigned short*)(ws + 573440); // 2304 B (total 575744)

  float* outP     = (float*)d_out;
  float* alphaOut = outP + (long)131072 * DD;

  prep_kernel<<<320, 256, 0, stream>>>(Aw, Ab, HMw, HMb, MEw, MEb, TFw, TFb,
                                       Afrag, Wfrag, Lut);
  fused_main<<<1024, 256, 0, stream>>>(hm, me, tf, Afrag, Wfrag, Lut,
                                       outP, alphaOut);
}